// Round 13
// baseline (196.308 us; speedup 1.0000x reference)
//
#include <hip/hip_runtime.h>
#include <hip/hip_bf16.h>

typedef __attribute__((ext_vector_type(4))) float f32x4;
typedef __attribute__((ext_vector_type(2))) float f32x2;
typedef __attribute__((ext_vector_type(8))) short bf16x8;

constexpr int D = 128;
constexpr int SB = 256;      // sort scatter blocks
constexpr int K4CAP = 8192;  // LDS stash per bucket (avg ~4096)
#define FEPS 1e-7f
#define FLN_EPS 1e-5f

__device__ __forceinline__ float groupReduceSum16(float x) {
#pragma unroll
  for (int off = 1; off < 16; off <<= 1) x += __shfl_xor(x, off, 64);
  return x;
}

__device__ __forceinline__ unsigned short f2bf(float x) {
  unsigned int u = __float_as_uint(x);
  u += 0x7fffu + ((u >> 16) & 1u);
  return (unsigned short)(u >> 16);
}

__device__ __forceinline__ unsigned int pack2(float a, float b) {
  return (unsigned int)f2bf(a) | ((unsigned int)f2bf(b) << 16);
}

__device__ __forceinline__ f32x2 unp(unsigned int x) {
  f32x2 r;
  r.x = __uint_as_float(x << 16);
  r.y = __uint_as_float(x & 0xffff0000u);
  return r;
}

// accumulator set: even features exact (shifted), odd features carry <=2^-8
// relative low-mantissa garbage (below bf16 noise; saves the mask op). R8-proven.
struct AccSet {
  f32x2 e0, o0, e1, o1;
};

__device__ __forceinline__ void accu(AccSet& s, uint4 u) {
  f32x2 t;
  t.x = __uint_as_float(u.x << 16);
  t.y = __uint_as_float(u.y << 16);
  s.e0 += t;
  t.x = __uint_as_float(u.x);
  t.y = __uint_as_float(u.y);
  s.o0 += t;
  t.x = __uint_as_float(u.z << 16);
  t.y = __uint_as_float(u.w << 16);
  s.e1 += t;
  t.x = __uint_as_float(u.z);
  t.y = __uint_as_float(u.w);
  s.o1 += t;
}

// ================= bucket-sort CSR build (no global atomics) =================

__global__ __launch_bounds__(1024) void k1_hist(const int* __restrict__ dst,
                                                int* __restrict__ bh, int E, int NB, int chunk) {
  __shared__ int h[256];
  int tid = threadIdx.x;
  if (tid < 256) h[tid] = 0;
  __syncthreads();
  int e0 = blockIdx.x * chunk;
  int e1 = min(e0 + chunk, E);
  for (int e = e0 + tid; e < e1; e += 1024) atomicAdd(&h[dst[e] >> 8], 1);
  __syncthreads();
  if (tid < NB) bh[tid * SB + blockIdx.x] = h[tid];
}

__global__ __launch_bounds__(1024) void k2_scan(int* __restrict__ bh,
                                                int* __restrict__ bucket_base, int NB, int E) {
  __shared__ int bsum[256];
  int tid = threadIdx.x, lane = tid & 63, wv = tid >> 6;
  for (int bin = wv; bin < NB; bin += 16) {
    int carry = 0;
    int* row = bh + bin * SB;
#pragma unroll
    for (int sgm = 0; sgm < 4; ++sgm) {
      int v = row[sgm * 64 + lane];
      int x = v;
#pragma unroll
      for (int off = 1; off < 64; off <<= 1) {
        int t = __shfl_up(x, off, 64);
        if (lane >= off) x += t;
      }
      row[sgm * 64 + lane] = carry + x - v;  // exclusive within bin
      carry += __shfl(x, 63, 64);
    }
    if (lane == 0) bsum[bin] = carry;
  }
  __syncthreads();
  if (wv == 0) {
    int carry = 0;
    for (int base = 0; base < NB; base += 64) {
      int v = (base + lane < NB) ? bsum[base + lane] : 0;
      int x = v;
#pragma unroll
      for (int off = 1; off < 64; off <<= 1) {
        int t = __shfl_up(x, off, 64);
        if (lane >= off) x += t;
      }
      if (base + lane < NB) {
        int excl = carry + x - v;
        bsum[base + lane] = excl;
        bucket_base[base + lane] = excl;
      }
      carry += __shfl(x, 63, 64);
    }
    if (lane == 0) bucket_base[NB] = E;
  }
  __syncthreads();
  for (int bin = wv; bin < NB; bin += 16) {
    int bb = bsum[bin];
    int* row = bh + bin * SB;
    for (int s = lane; s < SB; s += 64) row[s] += bb;
  }
}

__global__ __launch_bounds__(1024) void k4_csr(const unsigned int* __restrict__ ebuf,
                                               const int* __restrict__ bucket_base,
                                               int* __restrict__ rowptr,
                                               unsigned short* __restrict__ col, int N, int NB,
                                               int E) {
  __shared__ unsigned int stash[K4CAP];
  __shared__ int hist[256];
  __shared__ int cur[256];
  int b = blockIdx.x, tid = threadIdx.x;
  int e0 = bucket_base[b], e1 = bucket_base[b + 1];
  int cnt = e1 - e0;
  if (tid < 256) {
    hist[tid] = 0;
    cur[tid] = 0;
  }
  __syncthreads();
  for (int i = tid; i < cnt; i += 1024) {
    unsigned int u = ebuf[e0 + i];
    if (i < K4CAP) stash[i] = u;
    atomicAdd(&hist[u >> 16], 1);
  }
  __syncthreads();
  int lane = tid & 63;
  if (tid < 64) {
    int carry = 0;
#pragma unroll
    for (int sgm = 0; sgm < 4; ++sgm) {
      int v = hist[sgm * 64 + lane];
      int x = v;
#pragma unroll
      for (int off = 1; off < 64; off <<= 1) {
        int t = __shfl_up(x, off, 64);
        if (lane >= off) x += t;
      }
      hist[sgm * 64 + lane] = carry + x - v;
      carry += __shfl(x, 63, 64);
    }
  }
  __syncthreads();
  int node0 = b << 8;
  if (tid < 256 && node0 + tid < N) rowptr[node0 + tid] = e0 + hist[tid];
  if (b == 0 && tid == 0) rowptr[N] = E;
  for (int i = tid; i < cnt; i += 1024) {
    unsigned int u = (i < K4CAP) ? stash[i] : ebuf[e0 + i];
    int slot = u >> 16;
    int r = atomicAdd(&cur[slot], 1);
    col[e0 + hist[slot] + r] = (unsigned short)(u & 0xffff);
  }
}

// ======= bundle: K3 scatter + logmap layer 0 + W bf16 convert (independent) ======

__global__ __launch_bounds__(1024) void bundle_kernel(
    const int* __restrict__ src, const int* __restrict__ dst, const int* __restrict__ bh,
    unsigned int* __restrict__ ebuf, int E, int NB, int chunk, const float* __restrict__ xf,
    const float* __restrict__ Wf, const float* __restrict__ curv,
    unsigned short* __restrict__ xt, int N, unsigned short* __restrict__ W16, int nconv,
    int lmblocks) {
  __shared__ int scratch[512];
  int bid = blockIdx.x;
  int tid = threadIdx.x;
  if (bid < SB) {
    int* base = scratch;
    int* cur = scratch + 256;
    if (tid < 256) {
      base[tid] = (tid < NB) ? bh[tid * SB + bid] : 0;
      cur[tid] = 0;
    }
    __syncthreads();
    int e0 = bid * chunk;
    int e1 = min(e0 + chunk, E);
    for (int e = e0 + tid; e < e1; e += 1024) {
      int d = dst[e];
      int s = src[e];
      int bin = d >> 8;
      int r = atomicAdd(&cur[bin], 1);
      ebuf[base[bin] + r] = (unsigned int)(s & 0xffff) | ((unsigned int)(d & 255) << 16);
    }
  } else if (bid < SB + lmblocks) {
    int lane = tid & 63, wv = tid >> 6;
    int gl = lane & 15, g = lane >> 4;
    int row = (bid - SB) * 64 + wv * 4 + g;
    bool active = row < N;
    int rd = active ? row : N - 1;
    float c = fminf(fmaxf(curv[0], 0.1f), 10.0f);
    float K = 1.0f / c, sqrtK = sqrtf(K);
    const float4* xr = reinterpret_cast<const float4*>(xf + (size_t)rd * D + gl * 8);
    float4 f0 = xr[0];
    float4 f1 = xr[1];
    float ss = f0.x * f0.x + f0.y * f0.y + f0.z * f0.z + f0.w * f0.w + f1.x * f1.x +
               f1.y * f1.y + f1.z * f1.z + f1.w * f1.w;
    ss = groupReduceSum16(ss);
    float xnorm = sqrtf(ss);
    float t = sqrtf(K + ss);
    float theta = acoshf(fmaxf(t / sqrtK, 1.0f + FEPS));
    float scale = sqrtK * theta / fmaxf(xnorm, FEPS);
    if (active) {
      uint4 w;
      w.x = pack2(f0.x * scale, f0.y * scale);
      w.y = pack2(f0.z * scale, f0.w * scale);
      w.z = pack2(f1.x * scale, f1.y * scale);
      w.w = pack2(f1.z * scale, f1.w * scale);
      reinterpret_cast<uint4*>(xt)[(size_t)row * 16 + gl] = w;
    }
  } else {
    for (int i = tid * 4; i < nconv; i += 4096) {
      float4 f = *reinterpret_cast<const float4*>(Wf + i);
      uint2 o;
      o.x = pack2(f.x, f.y);
      o.y = pack2(f.z, f.w);
      *reinterpret_cast<uint2*>(W16 + i) = o;
    }
  }
}

// ==== XCD-sliced gather: slice = blockIdx&3 (XCD = blockIdx%8 round-robin) ====
// Each block: 64 nodes x 32 features (64B line-aligned slice). Working set per
// XCD = 3.2MB -> L2-resident. Writes fp32 partial sums msum[node][128].

__global__ __launch_bounds__(256) void gslice_kernel(const unsigned short* __restrict__ xt_in,
                                                     const int* __restrict__ rowptr,
                                                     const unsigned short* __restrict__ col,
                                                     float* __restrict__ msum, int N) {
  int bid = blockIdx.x;
  int slice = bid & 3;
  int chunk = bid >> 2;
  int tid = threadIdx.x;
  int lane = tid & 63, wv = tid >> 6;
  int q = lane & 3;       // lane within 4-lane group
  int grp = lane >> 2;    // 16 groups (nodes) per wave
  int gbase = lane & ~3;  // first lane of my group
  int node = chunk * 64 + wv * 16 + grp;
  bool active = node < N;
  int nd = active ? node : N - 1;

  int e0 = rowptr[nd], e1 = rowptr[nd + 1];
  int deg = e1 - e0;
  const unsigned short* cb = col + e0;

  AccSet S0, S1;
  S0.e0 = 0.f; S0.o0 = 0.f; S0.e1 = 0.f; S0.o1 = 0.f;
  S1.e0 = 0.f; S1.o0 = 0.f; S1.e1 = 0.f; S1.o1 = 0.f;

  const uint4* xtp = reinterpret_cast<const uint4*>(xt_in);
  int sb = slice * 4 + q;  // uint4 index within the 256B row
  int cidx = (q < deg) ? (int)cb[q] : 0;
  for (int base = 0; base < deg; base += 4) {
    int nb = base + 4;
    int cnext = (nb + q < deg) ? (int)cb[nb + q] : 0;  // prefetch next 4 indices
    int m = deg - base;
    if (m > 4) m = 4;
    if (m == 4) {
      int s0 = __shfl(cidx, gbase, 64);
      int s1 = __shfl(cidx, gbase + 1, 64);
      int s2 = __shfl(cidx, gbase + 2, 64);
      int s3 = __shfl(cidx, gbase + 3, 64);
      uint4 u0 = xtp[(size_t)s0 * 16 + sb];
      uint4 u1 = xtp[(size_t)s1 * 16 + sb];
      uint4 u2 = xtp[(size_t)s2 * 16 + sb];
      uint4 u3 = xtp[(size_t)s3 * 16 + sb];
      accu(S0, u0);
      accu(S1, u1);
      accu(S0, u2);
      accu(S1, u3);
    } else {
      for (int k = 0; k < m; ++k) {
        int s0 = __shfl(cidx, gbase + k, 64);
        accu(S0, xtp[(size_t)s0 * 16 + sb]);
      }
    }
    cidx = cnext;
  }
  f32x2 E0 = S0.e0 + S1.e0;
  f32x2 O0 = S0.o0 + S1.o0;
  f32x2 E1 = S0.e1 + S1.e1;
  f32x2 O1 = S0.o1 + S1.o1;

  if (active) {
    float4 w0, w1;
    w0.x = E0.x; w0.y = O0.x; w0.z = E0.y; w0.w = O0.y;
    w1.x = E1.x; w1.y = O1.x; w1.z = E1.y; w1.w = O1.y;
    float4* mp = reinterpret_cast<float4*>(msum + (size_t)node * D + slice * 32 + q * 8);
    mp[0] = w0;
    mp[1] = w1;
  }
}

// ==== epilogue: m = msum/deg; W·m + b + residual + LN + exp map (+next logmap) ====
// m in split precision (bf16 hi+lo), GEMM twice into one accumulator; ztile
// overlays hi/lo LDS. deg==0 -> zero aggregate (bias gated).

template <int MODE>
__global__ __launch_bounds__(256) void epi_kernel(const unsigned short* __restrict__ xt_in,
                                                  unsigned short* __restrict__ xt_out,
                                                  const float* __restrict__ msum,
                                                  const int* __restrict__ rowptr,
                                                  const float* __restrict__ gamma,
                                                  const float* __restrict__ beta,
                                                  const float* __restrict__ curv, int l,
                                                  const unsigned short* __restrict__ Wl,
                                                  const float* __restrict__ bias,
                                                  float* __restrict__ out, int N) {
  __shared__ char smem[16 * 136 * 2 * 2];
  unsigned short* xhi = reinterpret_cast<unsigned short*>(smem);
  unsigned short* xlo = xhi + 16 * 136;
  float* ztile = reinterpret_cast<float*>(smem);  // overlays (8448B <= 8704B)
  int tid = threadIdx.x;
  int lane = tid & 63;
  int gl = lane & 15, g = lane >> 4;
  int wid = tid >> 6;
  int node = blockIdx.x * 16 + wid * 4 + g;
  bool active = node < N;
  int nd = active ? node : N - 1;

  float c = fminf(fmaxf(curv[l], 0.1f), 10.0f);
  float K = 1.0f / c, sqrtK = sqrtf(K);

  int deg = rowptr[nd + 1] - rowptr[nd];
  float inv = 1.f / fmaxf((float)deg, 1.f);
  float flag = (deg > 0) ? 1.f : 0.f;

  const float4* mp = reinterpret_cast<const float4*>(msum + (size_t)nd * D + gl * 8);
  float4 ma = mp[0];
  float4 mb = mp[1];
  float a[8] = {ma.x, ma.y, ma.z, ma.w, mb.x, mb.y, mb.z, mb.w};

  // split-precision stash of m into hi/lo bf16 tiles
  int noderow = wid * 4 + g;
  {
    uint4 whi, wlo;
    unsigned int hb[8];
    float lo[8];
#pragma unroll
    for (int j = 0; j < 8; ++j) {
      float mj = a[j] * inv;
      unsigned short h = f2bf(mj);
      hb[j] = h;
      lo[j] = mj - __uint_as_float(((unsigned int)h) << 16);
    }
    whi.x = hb[0] | (hb[1] << 16);
    whi.y = hb[2] | (hb[3] << 16);
    whi.z = hb[4] | (hb[5] << 16);
    whi.w = hb[6] | (hb[7] << 16);
    wlo.x = pack2(lo[0], lo[1]);
    wlo.y = pack2(lo[2], lo[3]);
    wlo.z = pack2(lo[4], lo[5]);
    wlo.w = pack2(lo[6], lo[7]);
    *reinterpret_cast<uint4*>(&xhi[noderow * 136 + gl * 8]) = whi;
    *reinterpret_cast<uint4*>(&xlo[noderow * 136 + gl * 8]) = wlo;
  }
  __syncthreads();

  int rr = lane & 15, kg = lane >> 4;
  bf16x8 ah[4], al[4];
#pragma unroll
  for (int kb = 0; kb < 4; ++kb) {
    ah[kb] = *reinterpret_cast<const bf16x8*>(&xhi[rr * 136 + kb * 32 + kg * 8]);
    al[kb] = *reinterpret_cast<const bf16x8*>(&xlo[rr * 136 + kb * 32 + kg * 8]);
  }
  __syncthreads();  // xhi/xlo dead; ztile may overwrite

#pragma unroll
  for (int t = 0; t < 2; ++t) {
    int tcol = wid * 2 + t;
    f32x4 acc = {0.f, 0.f, 0.f, 0.f};
#pragma unroll
    for (int kb = 0; kb < 4; ++kb) {
      bf16x8 bfm = *reinterpret_cast<const bf16x8*>(Wl + (size_t)(tcol * 16 + rr) * D +
                                                    kb * 32 + kg * 8);
      acc = __builtin_amdgcn_mfma_f32_16x16x32_bf16(ah[kb], bfm, acc, 0, 0, 0);
      acc = __builtin_amdgcn_mfma_f32_16x16x32_bf16(al[kb], bfm, acc, 0, 0, 0);
    }
#pragma unroll
    for (int i = 0; i < 4; ++i) ztile[(kg * 4 + i) * 132 + tcol * 16 + rr] = acc[i];
  }
  __syncthreads();

  float4 wm0 = *reinterpret_cast<const float4*>(&ztile[noderow * 132 + gl * 8]);
  float4 wm1 = *reinterpret_cast<const float4*>(&ztile[noderow * 132 + gl * 8 + 4]);
  float4 bi0 = *reinterpret_cast<const float4*>(bias + l * D + gl * 8);
  float4 bi1 = *reinterpret_cast<const float4*>(bias + l * D + gl * 8 + 4);

  const uint4* xtp = reinterpret_cast<const uint4*>(xt_in);
  uint4 ut = xtp[(size_t)nd * 16 + gl];
  f32x2 utv[4];
  utv[0] = unp(ut.x);
  utv[1] = unp(ut.y);
  utv[2] = unp(ut.z);
  utv[3] = unp(ut.w);
  float v[8];
  v[0] = utv[0].x + wm0.x + bi0.x * flag;
  v[1] = utv[0].y + wm0.y + bi0.y * flag;
  v[2] = utv[1].x + wm0.z + bi0.z * flag;
  v[3] = utv[1].y + wm0.w + bi0.w * flag;
  v[4] = utv[2].x + wm1.x + bi1.x * flag;
  v[5] = utv[2].y + wm1.y + bi1.y * flag;
  v[6] = utv[3].x + wm1.z + bi1.z * flag;
  v[7] = utv[3].y + wm1.w + bi1.w * flag;

  float s1 = 0.f, s2 = 0.f;
#pragma unroll
  for (int j = 0; j < 8; ++j) {
    s1 += v[j];
    s2 += v[j] * v[j];
  }
  s1 = groupReduceSum16(s1);
  s2 = groupReduceSum16(s2);
  float mu = s1 * (1.f / 128.f);
  float var = fmaxf(s2 * (1.f / 128.f) - mu * mu, 0.f);
  float rstd = rsqrtf(var + FLN_EPS);

  float4 gm0 = *reinterpret_cast<const float4*>(gamma + l * D + gl * 8);
  float4 gm1 = *reinterpret_cast<const float4*>(gamma + l * D + gl * 8 + 4);
  float4 bt0 = *reinterpret_cast<const float4*>(beta + l * D + gl * 8);
  float4 bt1 = *reinterpret_cast<const float4*>(beta + l * D + gl * 8 + 4);
  float y[8];
  y[0] = (v[0] - mu) * rstd * gm0.x + bt0.x;
  y[1] = (v[1] - mu) * rstd * gm0.y + bt0.y;
  y[2] = (v[2] - mu) * rstd * gm0.z + bt0.z;
  y[3] = (v[3] - mu) * rstd * gm0.w + bt0.w;
  y[4] = (v[4] - mu) * rstd * gm1.x + bt1.x;
  y[5] = (v[5] - mu) * rstd * gm1.y + bt1.y;
  y[6] = (v[6] - mu) * rstd * gm1.z + bt1.z;
  y[7] = (v[7] - mu) * rstd * gm1.w + bt1.w;

  float ss = 0.f;
#pragma unroll
  for (int j = 0; j < 8; ++j) ss += y[j] * y[j];
  ss = groupReduceSum16(ss);
  float vn = sqrtf(ss);
  float sc = sqrtK * sinhf(vn / sqrtK) / fmaxf(vn, FEPS);

  if (MODE == 0) {
    if (active) {
      float4 o0, o1;
      o0.x = y[0] * sc;
      o0.y = y[1] * sc;
      o0.z = y[2] * sc;
      o0.w = y[3] * sc;
      o1.x = y[4] * sc;
      o1.y = y[5] * sc;
      o1.z = y[6] * sc;
      o1.w = y[7] * sc;
      float4* op = reinterpret_cast<float4*>(out + (size_t)node * D + gl * 8);
      op[0] = o0;
      op[1] = o1;
    }
  } else {
    float xn = sqrtK * sinhf(vn / sqrtK);
    float c2 = fminf(fmaxf(curv[l + 1], 0.1f), 10.0f);
    float K2 = 1.0f / c2, sqrtK2 = sqrtf(K2);
    float t2 = sqrtf(K2 + xn * xn);
    float theta = acoshf(fmaxf(t2 / sqrtK2, 1.0f + FEPS));
    float sc2 = sqrtK2 * theta / fmaxf(xn, FEPS);
    float st = sc * sc2;
    if (active) {
      uint4 w;
      w.x = pack2(y[0] * st, y[1] * st);
      w.y = pack2(y[2] * st, y[3] * st);
      w.z = pack2(y[4] * st, y[5] * st);
      w.w = pack2(y[6] * st, y[7] * st);
      reinterpret_cast<uint4*>(xt_out)[(size_t)node * 16 + gl] = w;
    }
  }
}

// ---------------- host ----------------

extern "C" void kernel_launch(void* const* d_in, const int* in_sizes, int n_in,
                              void* d_out, int out_size, void* d_ws, size_t ws_size,
                              hipStream_t stream) {
  const float* x_hyp = (const float*)d_in[0];
  const int* edge = (const int*)d_in[1];
  const float* W = (const float*)d_in[2];
  const float* b = (const float*)d_in[3];
  const float* gamma = (const float*)d_in[4];
  const float* beta = (const float*)d_in[5];
  const float* curv = (const float*)d_in[6];
  float* out = (float*)d_out;
  int N = in_sizes[0] / D;
  int E = in_sizes[1] / 2;
  int L = in_sizes[6];
  const int* src = edge;
  const int* dst = edge + E;

  char* p = (char*)d_ws;
  auto alloc = [&](size_t bytes) {
    char* r = p;
    p += (bytes + 255) & ~(size_t)255;
    return r;
  };
  int NB = (N + 255) >> 8;
  int chunk = (E + SB - 1) / SB;

  int* bh = (int*)alloc((size_t)256 * SB * 4);
  int* bucket_base = (int*)alloc((size_t)(NB + 1) * 4);
  unsigned int* ebuf = (unsigned int*)alloc((size_t)E * 4);
  int* rowptr = (int*)alloc((size_t)(N + 1) * 4);
  unsigned short* colp = (unsigned short*)alloc((size_t)E * 2);
  float* msum = (float*)alloc((size_t)N * D * 4);
  unsigned short* xtA = (unsigned short*)alloc((size_t)N * D * 2);
  unsigned short* xtB = (unsigned short*)alloc((size_t)N * D * 2);
  unsigned short* W16 = (unsigned short*)alloc((size_t)L * D * D * 2);

  int lmblocks = (N + 63) / 64;
  int nconv = L * D * D;

  k1_hist<<<SB, 1024, 0, stream>>>(dst, bh, E, NB, chunk);
  k2_scan<<<1, 1024, 0, stream>>>(bh, bucket_base, NB, E);
  bundle_kernel<<<SB + lmblocks + 1, 1024, 0, stream>>>(src, dst, bh, ebuf, E, NB, chunk,
                                                        x_hyp, W, curv, xtA, N, W16, nconv,
                                                        lmblocks);
  k4_csr<<<NB, 1024, 0, stream>>>(ebuf, bucket_base, rowptr, colp, N, NB, E);

  int gchunks = (N + 63) / 64;
  int gblocks = gchunks * 4;  // slice = blockIdx&3, chunk = blockIdx>>2
  int eblocks = (N + 15) / 16;

  unsigned short* cur = xtA;
  unsigned short* nxt = xtB;
  for (int l = 0; l < L; ++l) {
    gslice_kernel<<<gblocks, 256, 0, stream>>>(cur, rowptr, colp, msum, N);
    if (l < L - 1) {
      epi_kernel<1><<<eblocks, 256, 0, stream>>>(cur, nxt, msum, rowptr, gamma, beta, curv, l,
                                                 W16 + (size_t)l * D * D, b, out, N);
      unsigned short* tmp = cur;
      cur = nxt;
      nxt = tmp;
    } else {
      epi_kernel<0><<<eblocks, 256, 0, stream>>>(cur, nullptr, msum, rowptr, gamma, beta, curv,
                                                 l, W16 + (size_t)l * D * D, b, out, N);
    }
  }
}

// Round 14
// 141.126 us; speedup vs baseline: 1.3910x; 1.3910x over previous
//
#include <hip/hip_runtime.h>
#include <hip/hip_bf16.h>

typedef __attribute__((ext_vector_type(4))) float f32x4;
typedef __attribute__((ext_vector_type(2))) float f32x2;
typedef __attribute__((ext_vector_type(8))) short bf16x8;

constexpr int D = 128;
constexpr int SB = 256;      // sort scatter blocks
constexpr int K4CAP = 8192;  // LDS stash per bucket (avg ~4096)
#define FEPS 1e-7f
#define FLN_EPS 1e-5f

__device__ __forceinline__ float groupReduceSum16(float x) {
#pragma unroll
  for (int off = 1; off < 16; off <<= 1) x += __shfl_xor(x, off, 64);
  return x;
}

__device__ __forceinline__ unsigned short f2bf(float x) {
  unsigned int u = __float_as_uint(x);
  u += 0x7fffu + ((u >> 16) & 1u);
  return (unsigned short)(u >> 16);
}

__device__ __forceinline__ unsigned int pack2(float a, float b) {
  return (unsigned int)f2bf(a) | ((unsigned int)f2bf(b) << 16);
}

__device__ __forceinline__ f32x2 unp(unsigned int x) {
  f32x2 r;
  r.x = __uint_as_float(x << 16);
  r.y = __uint_as_float(x & 0xffff0000u);
  return r;
}

// accumulator set: even features exact (shifted), odd features carry <=2^-8
// relative low-mantissa garbage (below bf16 noise; saves the mask op).
struct AccSet {
  f32x2 e0, o0, e1, o1;
};

__device__ __forceinline__ void accu(AccSet& s, uint4 u) {
  f32x2 t;
  t.x = __uint_as_float(u.x << 16);
  t.y = __uint_as_float(u.y << 16);
  s.e0 += t;
  t.x = __uint_as_float(u.x);
  t.y = __uint_as_float(u.y);
  s.o0 += t;
  t.x = __uint_as_float(u.z << 16);
  t.y = __uint_as_float(u.w << 16);
  s.e1 += t;
  t.x = __uint_as_float(u.z);
  t.y = __uint_as_float(u.w);
  s.o1 += t;
}

// ================= bucket-sort CSR build (no global atomics) =================

// K1: per-block LDS histogram of dst>>8; write [bin][block] count matrix.
__global__ __launch_bounds__(1024) void k1_hist(const int* __restrict__ dst,
                                                int* __restrict__ bh, int E, int NB, int chunk) {
  __shared__ int h[256];
  int tid = threadIdx.x;
  if (tid < 256) h[tid] = 0;
  __syncthreads();
  int e0 = blockIdx.x * chunk;
  int e1 = min(e0 + chunk, E);
  for (int e = e0 + tid; e < e1; e += 1024) atomicAdd(&h[dst[e] >> 8], 1);
  __syncthreads();
  if (tid < NB) bh[tid * SB + blockIdx.x] = h[tid];
}

// K2: in-place scan bh rows (bin-major) -> per-(block,bin) bases; bucket bases out.
__global__ __launch_bounds__(1024) void k2_scan(int* __restrict__ bh,
                                                int* __restrict__ bucket_base, int NB, int E) {
  __shared__ int bsum[256];
  int tid = threadIdx.x, lane = tid & 63, wv = tid >> 6;
  for (int bin = wv; bin < NB; bin += 16) {
    int carry = 0;
    int* row = bh + bin * SB;
#pragma unroll
    for (int sgm = 0; sgm < 4; ++sgm) {
      int v = row[sgm * 64 + lane];
      int x = v;
#pragma unroll
      for (int off = 1; off < 64; off <<= 1) {
        int t = __shfl_up(x, off, 64);
        if (lane >= off) x += t;
      }
      row[sgm * 64 + lane] = carry + x - v;  // exclusive within bin
      carry += __shfl(x, 63, 64);
    }
    if (lane == 0) bsum[bin] = carry;
  }
  __syncthreads();
  if (wv == 0) {  // exclusive scan of bucket totals
    int carry = 0;
    for (int base = 0; base < NB; base += 64) {
      int v = (base + lane < NB) ? bsum[base + lane] : 0;
      int x = v;
#pragma unroll
      for (int off = 1; off < 64; off <<= 1) {
        int t = __shfl_up(x, off, 64);
        if (lane >= off) x += t;
      }
      if (base + lane < NB) {
        int excl = carry + x - v;
        bsum[base + lane] = excl;
        bucket_base[base + lane] = excl;
      }
      carry += __shfl(x, 63, 64);
    }
    if (lane == 0) bucket_base[NB] = E;
  }
  __syncthreads();
  for (int bin = wv; bin < NB; bin += 16) {
    int bb = bsum[bin];
    int* row = bh + bin * SB;
    for (int s = lane; s < SB; s += 64) row[s] += bb;
  }
}

// K4: one block per bucket -> packed CSR (rowptr + ushort col).
__global__ __launch_bounds__(1024) void k4_csr(const unsigned int* __restrict__ ebuf,
                                               const int* __restrict__ bucket_base,
                                               int* __restrict__ rowptr,
                                               unsigned short* __restrict__ col, int N, int NB,
                                               int E) {
  __shared__ unsigned int stash[K4CAP];
  __shared__ int hist[256];
  __shared__ int cur[256];
  int b = blockIdx.x, tid = threadIdx.x;
  int e0 = bucket_base[b], e1 = bucket_base[b + 1];
  int cnt = e1 - e0;
  if (tid < 256) {
    hist[tid] = 0;
    cur[tid] = 0;
  }
  __syncthreads();
  for (int i = tid; i < cnt; i += 1024) {
    unsigned int u = ebuf[e0 + i];
    if (i < K4CAP) stash[i] = u;
    atomicAdd(&hist[u >> 16], 1);
  }
  __syncthreads();
  int lane = tid & 63;
  if (tid < 64) {  // wave 0: exclusive scan hist[256]
    int carry = 0;
#pragma unroll
    for (int sgm = 0; sgm < 4; ++sgm) {
      int v = hist[sgm * 64 + lane];
      int x = v;
#pragma unroll
      for (int off = 1; off < 64; off <<= 1) {
        int t = __shfl_up(x, off, 64);
        if (lane >= off) x += t;
      }
      hist[sgm * 64 + lane] = carry + x - v;
      carry += __shfl(x, 63, 64);
    }
  }
  __syncthreads();
  int node0 = b << 8;
  if (tid < 256 && node0 + tid < N) rowptr[node0 + tid] = e0 + hist[tid];
  if (b == 0 && tid == 0) rowptr[N] = E;
  for (int i = tid; i < cnt; i += 1024) {
    unsigned int u = (i < K4CAP) ? stash[i] : ebuf[e0 + i];
    int slot = u >> 16;
    int r = atomicAdd(&cur[slot], 1);
    col[e0 + hist[slot] + r] = (unsigned short)(u & 0xffff);
  }
}

// ================= GEMM layer-0 body (1024 threads, 16 waves x 16 rows) ======
// Reads fp32 x, fuses log_map (row-norm in-register), writes xt16 + xl.

__device__ __forceinline__ void gemm0_body(int gbid, unsigned short* Wlds,
                                           const float* __restrict__ xf,
                                           const float* __restrict__ Wf,
                                           const float* __restrict__ bias,
                                           const float* __restrict__ curv,
                                           unsigned short* __restrict__ xt,
                                           unsigned short* __restrict__ xl, int N) {
  for (int idx = threadIdx.x; idx < 2048; idx += 1024) {
    int lanei = idx & 63, kbt = idx >> 6;
    int kb = kbt & 3, tcol = kbt >> 2;
    int g = lanei >> 4, r = lanei & 15;
    const float* s = Wf + (size_t)(tcol * 16 + r) * D + kb * 32 + g * 8;
    float4 f0 = *reinterpret_cast<const float4*>(s);
    float4 f1 = *reinterpret_cast<const float4*>(s + 4);
    uint4 u;
    u.x = pack2(f0.x, f0.y);
    u.y = pack2(f0.z, f0.w);
    u.z = pack2(f1.x, f1.y);
    u.w = pack2(f1.z, f1.w);
    *reinterpret_cast<uint4*>(&Wlds[idx * 8]) = u;
  }
  __syncthreads();
  int lane = threadIdx.x & 63;
  int trow = gbid * 16 + (threadIdx.x >> 6);
  int n0 = trow * 16;
  if (n0 >= N) return;
  int g = lane >> 4, r = lane & 15;
  int ar = n0 + r;
  if (ar > N - 1) ar = N - 1;

  bf16x8 af[4];
  float c = fminf(fmaxf(curv[0], 0.1f), 10.0f);
  float K = 1.0f / c, sqrtK = sqrtf(K);
  float4 fa[4][2];
  float ss = 0.f;
#pragma unroll
  for (int kb = 0; kb < 4; ++kb) {
    const float4* xr = reinterpret_cast<const float4*>(xf + (size_t)ar * D + kb * 32 + g * 8);
    fa[kb][0] = xr[0];
    fa[kb][1] = xr[1];
    ss += fa[kb][0].x * fa[kb][0].x + fa[kb][0].y * fa[kb][0].y + fa[kb][0].z * fa[kb][0].z +
          fa[kb][0].w * fa[kb][0].w;
    ss += fa[kb][1].x * fa[kb][1].x + fa[kb][1].y * fa[kb][1].y + fa[kb][1].z * fa[kb][1].z +
          fa[kb][1].w * fa[kb][1].w;
  }
  ss += __shfl_xor(ss, 16, 64);
  ss += __shfl_xor(ss, 32, 64);
  float xnorm = sqrtf(ss);
  float t = sqrtf(K + ss);
  float theta = acoshf(fmaxf(t / sqrtK, 1.0f + FEPS));
  float scale = sqrtK * theta / fmaxf(xnorm, FEPS);
#pragma unroll
  for (int kb = 0; kb < 4; ++kb) {
    union { bf16x8 v; uint4 u; } cv;
    cv.u.x = pack2(fa[kb][0].x * scale, fa[kb][0].y * scale);
    cv.u.y = pack2(fa[kb][0].z * scale, fa[kb][0].w * scale);
    cv.u.z = pack2(fa[kb][1].x * scale, fa[kb][1].y * scale);
    cv.u.w = pack2(fa[kb][1].z * scale, fa[kb][1].w * scale);
    af[kb] = cv.v;
    *reinterpret_cast<uint4*>(xt + (size_t)ar * D + kb * 32 + g * 8) = cv.u;
  }

  int colj = lane & 15, rb = (lane >> 4) * 4;
#pragma unroll
  for (int tcol = 0; tcol < 8; ++tcol) {
    f32x4 acc = {0.f, 0.f, 0.f, 0.f};
#pragma unroll
    for (int kb = 0; kb < 4; ++kb) {
      bf16x8 bfm = *reinterpret_cast<const bf16x8*>(&Wlds[((tcol * 4 + kb) * 64 + lane) * 8]);
      acc = __builtin_amdgcn_mfma_f32_16x16x32_bf16(af[kb], bfm, acc, 0, 0, 0);
    }
    float bv = bias[tcol * 16 + colj];
#pragma unroll
    for (int i = 0; i < 4; ++i) {
      int row = n0 + rb + i;
      if (row < N) xl[(size_t)row * D + tcol * 16 + colj] = f2bf(acc[i] + bv);
    }
  }
}

// bundle: [0,SB) K3 scatter; [SB,SB+g) layer-0 GEMM; last block converts W1..WL-1.
__global__ __launch_bounds__(1024) void bundle_kernel(
    const int* __restrict__ src, const int* __restrict__ dst, const int* __restrict__ bh,
    unsigned int* __restrict__ ebuf, int E, int NB, int chunk, const float* __restrict__ xf,
    const float* __restrict__ Wf, const float* __restrict__ bias,
    const float* __restrict__ curv, unsigned short* __restrict__ xt,
    unsigned short* __restrict__ xl, int N, unsigned short* __restrict__ W16, int nconv,
    int gblocks) {
  __shared__ unsigned short Wlds[128 * 128];  // 32KB (aliased by scatter blocks)
  int bid = blockIdx.x;
  if (bid < SB) {
    int* base = (int*)Wlds;
    int* cur = base + 256;
    int tid = threadIdx.x;
    if (tid < 256) {
      base[tid] = (tid < NB) ? bh[tid * SB + bid] : 0;
      cur[tid] = 0;
    }
    __syncthreads();
    int e0 = bid * chunk;
    int e1 = min(e0 + chunk, E);
    for (int e = e0 + tid; e < e1; e += 1024) {
      int d = dst[e];
      int s = src[e];
      int bin = d >> 8;
      int r = atomicAdd(&cur[bin], 1);
      ebuf[base[bin] + r] = (unsigned int)(s & 0xffff) | ((unsigned int)(d & 255) << 16);
    }
  } else if (bid < SB + gblocks) {
    gemm0_body(bid - SB, Wlds, xf, Wf, bias, curv, xt, xl, N);
  } else {
    for (int i = threadIdx.x * 4; i < nconv; i += 4096) {
      float4 f = *reinterpret_cast<const float4*>(Wf + D * D + i);
      uint2 o;
      o.x = pack2(f.x, f.y);
      o.y = pack2(f.z, f.w);
      *reinterpret_cast<uint2*>(W16 + i) = o;
    }
  }
}

// ================= GEMM layer>=1 (bf16 in, bf16 W16) =================

__global__ __launch_bounds__(1024) void gemm_kernel(const unsigned short* __restrict__ A,
                                                    const unsigned short* __restrict__ W16,
                                                    const float* __restrict__ bias, int l,
                                                    unsigned short* __restrict__ xl, int N) {
  __shared__ unsigned short Wlds[128 * 128];
  const unsigned short* Wp = W16 + (size_t)(l - 1) * D * D;
  for (int idx = threadIdx.x; idx < 2048; idx += 1024) {
    int lanei = idx & 63, kbt = idx >> 6;
    int kb = kbt & 3, tcol = kbt >> 2;
    int g = lanei >> 4, r = lanei & 15;
    *reinterpret_cast<uint4*>(&Wlds[idx * 8]) =
        *reinterpret_cast<const uint4*>(Wp + (size_t)(tcol * 16 + r) * D + kb * 32 + g * 8);
  }
  __syncthreads();
  int lane = threadIdx.x & 63;
  int trow = blockIdx.x * 16 + (threadIdx.x >> 6);
  int n0 = trow * 16;
  if (n0 >= N) return;
  int g = lane >> 4, r = lane & 15;
  int ar = n0 + r;
  if (ar > N - 1) ar = N - 1;
  bf16x8 af[4];
#pragma unroll
  for (int kb = 0; kb < 4; ++kb)
    af[kb] = *reinterpret_cast<const bf16x8*>(A + (size_t)ar * D + kb * 32 + g * 8);
  int colj = lane & 15, rb = (lane >> 4) * 4;
#pragma unroll
  for (int tcol = 0; tcol < 8; ++tcol) {
    f32x4 acc = {0.f, 0.f, 0.f, 0.f};
#pragma unroll
    for (int kb = 0; kb < 4; ++kb) {
      bf16x8 bfm = *reinterpret_cast<const bf16x8*>(&Wlds[((tcol * 4 + kb) * 64 + lane) * 8]);
      acc = __builtin_amdgcn_mfma_f32_16x16x32_bf16(af[kb], bfm, acc, 0, 0, 0);
    }
    float bv = bias[l * D + tcol * 16 + colj];
#pragma unroll
    for (int i = 0; i < 4; ++i) {
      int row = n0 + rb + i;
      if (row < N) xl[(size_t)row * D + tcol * 16 + colj] = f2bf(acc[i] + bv);
    }
  }
}

// ======== aggregate + residual + LN + exp map (+fused next logmap) ========
// Lean: 4 nodes/wave, 16 lanes x 16B per edge row, 4-deep unroll, cidx
// double-buffer prefetch. No LDS, minimal VGPR.
// MODE 0: final layer, write fp32 out. MODE 1: write bf16 xt (in place) with
// fused exp_map(c_l) o log_map(c_{l+1}) combined scale.

template <int MODE>
__global__ __launch_bounds__(256) void agg_kernel(const unsigned short* __restrict__ xl_in,
                                                  unsigned short* __restrict__ xt,
                                                  const int* __restrict__ rowptr,
                                                  const unsigned short* __restrict__ col,
                                                  const float* __restrict__ gamma,
                                                  const float* __restrict__ beta,
                                                  const float* __restrict__ curv, int l,
                                                  float* __restrict__ out, int N) {
  int tid = threadIdx.x;
  int lane = tid & 63;
  int gl = lane & 15, g = lane >> 4;
  int wid = tid >> 6;
  int node = blockIdx.x * 16 + wid * 4 + g;
  bool active = node < N;
  int nd = active ? node : N - 1;

  float c = fminf(fmaxf(curv[l], 0.1f), 10.0f);
  float K = 1.0f / c, sqrtK = sqrtf(K);

  int e0 = rowptr[nd], e1 = rowptr[nd + 1];
  int deg = e1 - e0;
  const unsigned short* cb = col + e0;

  AccSet S0, S1;
  S0.e0 = 0.f; S0.o0 = 0.f; S0.e1 = 0.f; S0.o1 = 0.f;
  S1.e0 = 0.f; S1.o0 = 0.f; S1.e1 = 0.f; S1.o1 = 0.f;

  const uint4* xlp = reinterpret_cast<const uint4*>(xl_in);
  int cidx = (gl < deg) ? (int)cb[gl] : 0;
  for (int base = 0; base < deg; base += 16) {
    int nb = base + 16;
    int cnext = (nb + gl < deg) ? (int)cb[nb + gl] : 0;  // prefetch next batch
    int m = deg - base;
    if (m > 16) m = 16;
    int k = 0;
    for (; k + 4 <= m; k += 4) {
      int s0 = __shfl(cidx, g * 16 + k, 64);
      int s1 = __shfl(cidx, g * 16 + k + 1, 64);
      int s2 = __shfl(cidx, g * 16 + k + 2, 64);
      int s3 = __shfl(cidx, g * 16 + k + 3, 64);
      uint4 u0 = xlp[(size_t)s0 * 16 + gl];
      uint4 u1 = xlp[(size_t)s1 * 16 + gl];
      uint4 u2 = xlp[(size_t)s2 * 16 + gl];
      uint4 u3 = xlp[(size_t)s3 * 16 + gl];
      accu(S0, u0);
      accu(S1, u1);
      accu(S0, u2);
      accu(S1, u3);
    }
    for (; k < m; ++k) {
      int s0 = __shfl(cidx, g * 16 + k, 64);
      uint4 u0 = xlp[(size_t)s0 * 16 + gl];
      accu(S0, u0);
    }
    cidx = cnext;
  }
  f32x2 E0 = S0.e0 + S1.e0;
  f32x2 O0 = S0.o0 + S1.o0;
  f32x2 E1 = S0.e1 + S1.e1;
  f32x2 O1 = S0.o1 + S1.o1;
  float a[8] = {E0.x, O0.x, E0.y, O0.y, E1.x, O1.x, E1.y, O1.y};

  float inv = 1.f / fmaxf((float)deg, 1.f);
  uint4 ut = reinterpret_cast<const uint4*>(xt)[(size_t)nd * 16 + gl];
  f32x2 utv[4];
  utv[0] = unp(ut.x);
  utv[1] = unp(ut.y);
  utv[2] = unp(ut.z);
  utv[3] = unp(ut.w);
  float v[8];
#pragma unroll
  for (int j = 0; j < 4; ++j) {
    v[2 * j] = utv[j].x + a[2 * j] * inv;
    v[2 * j + 1] = utv[j].y + a[2 * j + 1] * inv;
  }

  float s1 = 0.f, s2 = 0.f;
#pragma unroll
  for (int j = 0; j < 8; ++j) {
    s1 += v[j];
    s2 += v[j] * v[j];
  }
  s1 = groupReduceSum16(s1);
  s2 = groupReduceSum16(s2);
  float mu = s1 * (1.f / 128.f);
  float var = fmaxf(s2 * (1.f / 128.f) - mu * mu, 0.f);
  float rstd = rsqrtf(var + FLN_EPS);

  float4 gm0 = *reinterpret_cast<const float4*>(gamma + l * D + gl * 8);
  float4 gm1 = *reinterpret_cast<const float4*>(gamma + l * D + gl * 8 + 4);
  float4 bt0 = *reinterpret_cast<const float4*>(beta + l * D + gl * 8);
  float4 bt1 = *reinterpret_cast<const float4*>(beta + l * D + gl * 8 + 4);
  float y[8];
  y[0] = (v[0] - mu) * rstd * gm0.x + bt0.x;
  y[1] = (v[1] - mu) * rstd * gm0.y + bt0.y;
  y[2] = (v[2] - mu) * rstd * gm0.z + bt0.z;
  y[3] = (v[3] - mu) * rstd * gm0.w + bt0.w;
  y[4] = (v[4] - mu) * rstd * gm1.x + bt1.x;
  y[5] = (v[5] - mu) * rstd * gm1.y + bt1.y;
  y[6] = (v[6] - mu) * rstd * gm1.z + bt1.z;
  y[7] = (v[7] - mu) * rstd * gm1.w + bt1.w;

  float ss = 0.f;
#pragma unroll
  for (int j = 0; j < 8; ++j) ss += y[j] * y[j];
  ss = groupReduceSum16(ss);
  float vn = sqrtf(ss);
  float sc = sqrtK * sinhf(vn / sqrtK) / fmaxf(vn, FEPS);

  if (MODE == 0) {
    if (active) {
      float4 o0, o1;
      o0.x = y[0] * sc;
      o0.y = y[1] * sc;
      o0.z = y[2] * sc;
      o0.w = y[3] * sc;
      o1.x = y[4] * sc;
      o1.y = y[5] * sc;
      o1.z = y[6] * sc;
      o1.w = y[7] * sc;
      float4* op = reinterpret_cast<float4*>(out + (size_t)node * D + gl * 8);
      op[0] = o0;
      op[1] = o1;
    }
  } else {
    // fused: x = exp_map(y, c_l); xt_next = log_map(x, c_{l+1})
    float xn = sqrtK * sinhf(vn / sqrtK);  // ||x|| (exact since ||y|| = vn)
    float c2 = fminf(fmaxf(curv[l + 1], 0.1f), 10.0f);
    float K2 = 1.0f / c2, sqrtK2 = sqrtf(K2);
    float t2 = sqrtf(K2 + xn * xn);
    float theta = acoshf(fmaxf(t2 / sqrtK2, 1.0f + FEPS));
    float sc2 = sqrtK2 * theta / fmaxf(xn, FEPS);
    float st = sc * sc2;
    if (active) {
      uint4 w;
      w.x = pack2(y[0] * st, y[1] * st);
      w.y = pack2(y[2] * st, y[3] * st);
      w.z = pack2(y[4] * st, y[5] * st);
      w.w = pack2(y[6] * st, y[7] * st);
      reinterpret_cast<uint4*>(xt)[(size_t)node * 16 + gl] = w;
    }
  }
}

// ---------------- host ----------------

extern "C" void kernel_launch(void* const* d_in, const int* in_sizes, int n_in,
                              void* d_out, int out_size, void* d_ws, size_t ws_size,
                              hipStream_t stream) {
  const float* x_hyp = (const float*)d_in[0];
  const int* edge = (const int*)d_in[1];
  const float* W = (const float*)d_in[2];
  const float* b = (const float*)d_in[3];
  const float* gamma = (const float*)d_in[4];
  const float* beta = (const float*)d_in[5];
  const float* curv = (const float*)d_in[6];
  float* out = (float*)d_out;
  int N = in_sizes[0] / D;
  int E = in_sizes[1] / 2;
  int L = in_sizes[6];
  const int* src = edge;
  const int* dst = edge + E;

  char* p = (char*)d_ws;
  auto alloc = [&](size_t bytes) {
    char* r = p;
    p += (bytes + 255) & ~(size_t)255;
    return r;
  };
  int NB = (N + 255) >> 8;
  int chunk = (E + SB - 1) / SB;

  int* bh = (int*)alloc((size_t)256 * SB * 4);
  int* bucket_base = (int*)alloc((size_t)(NB + 1) * 4);
  unsigned int* ebuf = (unsigned int*)alloc((size_t)E * 4);
  int* rowptr = (int*)alloc((size_t)(N + 1) * 4);
  unsigned short* colp = (unsigned short*)alloc((size_t)E * 2);
  unsigned short* xt16 = (unsigned short*)alloc((size_t)N * D * 2);
  unsigned short* xlA = (unsigned short*)alloc((size_t)N * D * 2);
  unsigned short* xlB = (unsigned short*)alloc((size_t)N * D * 2);
  unsigned short* W16 = (unsigned short*)alloc((size_t)(L > 1 ? (L - 1) : 1) * D * D * 2);

  int g1024 = ((N + 15) / 16 + 15) / 16;
  int nconv = (L - 1) * D * D;

  k1_hist<<<SB, 1024, 0, stream>>>(dst, bh, E, NB, chunk);
  k2_scan<<<1, 1024, 0, stream>>>(bh, bucket_base, NB, E);
  // bundle: K3 scatter + layer-0 logmap+GEMM + W bf16 convert (all independent)
  bundle_kernel<<<SB + g1024 + 1, 1024, 0, stream>>>(src, dst, bh, ebuf, E, NB, chunk, x_hyp,
                                                     W, b, curv, xt16, xlA, N, W16, nconv,
                                                     g1024);
  k4_csr<<<NB, 1024, 0, stream>>>(ebuf, bucket_base, rowptr, colp, N, NB, E);

  unsigned short* xl_cur = xlA;
  unsigned short* xl_nxt = xlB;
  for (int l = 0; l < L; ++l) {
    if (l < L - 1) {
      agg_kernel<1><<<(N + 15) / 16, 256, 0, stream>>>(xl_cur, xt16, rowptr, colp, gamma, beta,
                                                       curv, l, out, N);
      gemm_kernel<<<g1024, 1024, 0, stream>>>(xt16, W16, b, l + 1, xl_nxt, N);
      unsigned short* tmp = xl_cur;
      xl_cur = xl_nxt;
      xl_nxt = tmp;
    } else {
      agg_kernel<0><<<(N + 15) / 16, 256, 0, stream>>>(xl_cur, xt16, rowptr, colp, gamma, beta,
                                                       curv, l, out, N);
    }
  }
}